// Round 12
// baseline (446.422 us; speedup 1.0000x reference)
//
#include <hip/hip_runtime.h>
#include <hip/hip_bf16.h>
#include <math.h>

// Problem constants (B=4, S=4096 -> T=16384 tokens)
#define TOKENS 16384
#define HD 1024
#define FD 2048
#define NEXP 8
#define RP_MAX (264 * 128)   // max padded routed rows
#define MAX_MT 264           // max 128-row m-tiles (divisible by 8 for XCD swizzle)
#define NTN1 16              // gemm1 n-tiles: FD/128
#define NTN2 8               // gemm2 n-tiles: HD/128

// mega-prep block ranges (1024 threads/block): routing FIRST (serial block
// overlaps the BW-bound rest), then convert_x, then w1 transpose.
#define NB_CONV 2048
#define NB_W1   1024
#define NB_PREP (1 + NB_CONV + NB_W1)

// gemm1 launch: GEMM blocks + fused w2-transpose blocks (only gemm2 needs W2t)
#define G1_BLOCKS (MAX_MT * NTN1)    // 4224
#define NB_W2     1024               // 8 experts x 16 k-tiles x 8 n-tiles (128x128)

typedef __bf16 bf16x8 __attribute__((ext_vector_type(8)));
typedef float f32x4 __attribute__((ext_vector_type(4)));
typedef unsigned short u16;
typedef unsigned int u32;
typedef unsigned long long u64;

__device__ __forceinline__ u16 f2bf(float f) {
    union { float f; u32 u; } v; v.f = f;
    return (u16)((v.u + 0x7FFFu + ((v.u >> 16) & 1u)) >> 16);
}

// pack two f32 -> two bf16 in one instruction (lo = src0, hi = src1)
__device__ __forceinline__ u32 pk_bf16(float lo, float hi) {
    u32 p;
    asm("v_cvt_pk_bf16_f32 %0, %1, %2" : "=v"(p) : "v"(lo), "v"(hi));
    return p;
}

// gelu tanh/sigmoid form: v * sigmoid(1.5957692*(v + 0.044715 v^3))
__device__ __forceinline__ float gelu_f(float v) {
    float u = __builtin_fmaf(0.044715f * v * v, v, v);   // v + 0.044715 v^3
    float ez = __builtin_amdgcn_exp2f(-2.302208f * u);   // exp(-1.5957692 u)
    return v * __builtin_amdgcn_rcpf(1.0f + ez);
}

#define GLOAD16(g, l) __builtin_amdgcn_global_load_lds( \
    (const __attribute__((address_space(1))) u32*)(g),  \
    (__attribute__((address_space(3))) u32*)(l), 16, 0, 0)

// ==================================================================
// mega-prep: routing (bid 0) | convert_x | w1 transpose
// ==================================================================
__global__ __launch_bounds__(1024) void mega_prep(
    const float* __restrict__ x, u16* __restrict__ xb,
    const float* __restrict__ w1, u16* __restrict__ w1t,
    const int* __restrict__ te,
    int* sorted_rid, int* inv, int* tileE, int* tileRow,
    int* numTiles, int* padcum)
{
    __shared__ __align__(16) char ldsT[32768];          // 128 rows x 32 slots x 8B
    __shared__ int cntS[NEXP], offsS[NEXP], fillS[NEXP], padS[NEXP], ntS;
    int b = blockIdx.x;
    int tid = threadIdx.x;

    if (b == 0) {
        // ---- routing (single block, 1024 threads = 16 waves) — dispatched
        // first so its serial latency overlaps the BW-bound blocks below.
        int lane = tid & 63;
        if (tid < NEXP) cntS[tid] = 0;
        __syncthreads();
        int h[NEXP] = {0, 0, 0, 0, 0, 0, 0, 0};
        for (int j = tid; j < TOKENS * 2; j += 1024) {
            int v = te[j];
            #pragma unroll
            for (int e = 0; e < NEXP; e++) h[e] += (v == e);
        }
        #pragma unroll
        for (int e = 0; e < NEXP; e++) {
            int s = h[e];
            #pragma unroll
            for (int o = 32; o > 0; o >>= 1) s += __shfl_down(s, o, 64);
            if (lane == 0 && s) atomicAdd(&cntS[e], s);
        }
        __syncthreads();
        if (tid == 0) {
            int o = 0, t = 0, pc = 0;
            for (int e = 0; e < NEXP; e++) {
                offsS[e] = o; fillS[e] = 0;
                int pad = o - pc;
                padS[e] = pad; padcum[e] = pad;
                int c = cntS[e];
                int nt = (c + 127) >> 7;
                for (int i = 0; i < nt; i++) { tileE[t] = e; tileRow[t] = o + i * 128; t++; }
                o += nt * 128; pc += c;
            }
            ntS = t;
            *numTiles = t;
        }
        __syncthreads();
        int tot = ntS * 128;
        for (int i = tid; i < tot; i += 1024) sorted_rid[i] = -1;
        __syncthreads();
        for (int j = tid; j < TOKENS * 2; j += 1024) {   // full waves always
            int v = te[j];
            int base = 0;
            #pragma unroll
            for (int e = 0; e < NEXP; e++) {
                unsigned long long m = __ballot(v == e);
                if (m) {
                    int ldr = (int)__builtin_ctzll(m);
                    int bb = 0;
                    if (lane == ldr) bb = atomicAdd(&fillS[e], __popcll(m));
                    bb = __shfl(bb, ldr, 64);
                    if (v == e) base = bb + (int)__popcll(m & ((1ull << lane) - 1ull));
                }
            }
            int p = offsS[v] + base;
            sorted_rid[p] = j;
            inv[j] = p - padS[v];            // compacted (pad-free) slot
        }
        return;
    }
    if (b <= NB_CONV) {                      // ---- convert x -> bf16
        int i = (b - 1) * 1024 + tid;        // one thread = 8 elems
        const float4* xv = (const float4*)x;
        float4 a = xv[i * 2], c = xv[i * 2 + 1];
        union { u16 s[8]; uint4 v; } o;
        o.s[0] = f2bf(a.x); o.s[1] = f2bf(a.y); o.s[2] = f2bf(a.z); o.s[3] = f2bf(a.w);
        o.s[4] = f2bf(c.x); o.s[5] = f2bf(c.y); o.s[6] = f2bf(c.z); o.s[7] = f2bf(c.w);
        *(uint4*)(xb + (size_t)i * 8) = o.v;
        return;
    }
    // ---- w1 transpose [E][HD][FD] -> [E][FD][HD], 128x128 tiles
    {
        int bb = b - 1 - NB_CONV;
        int e = bb >> 7; int r = bb & 127;   // 8 k-tiles x 16 n-tiles
        int n0 = (r & 15) * 128, k0 = (r >> 4) * 128;
        const int K = HD, N = FD;
        const float* s = w1 + (size_t)e * K * N + (size_t)k0 * N + n0;
        u16* d = w1t + (size_t)e * N * K + (size_t)n0 * K + k0;
        int tx = tid & 31, ty = tid >> 5;
        #pragma unroll
        for (int p = 0; p < 4; p++) {
            int k = p * 32 + ty;
            float4 v = *(const float4*)(s + (size_t)k * N + tx * 4);
            union { u16 q[4]; u64 u; } o;
            o.q[0] = f2bf(v.x); o.q[1] = f2bf(v.y); o.q[2] = f2bf(v.z); o.q[3] = f2bf(v.w);
            int phys = tx ^ (k & 31);
            *(u64*)(ldsT + k * 256 + phys * 8) = o.u;
        }
        __syncthreads();
        int tx2 = tid & 15, ty2 = tid >> 4;
        #pragma unroll
        for (int p = 0; p < 2; p++) {
            int n = p * 64 + ty2;
            union { u16 q[8]; uint4 u; } o;
            #pragma unroll
            for (int j = 0; j < 8; j++) {
                int k = tx2 * 8 + j;
                int phys = (n >> 2) ^ (k & 31);
                o.q[j] = *(const u16*)(ldsT + k * 256 + phys * 8 + (n & 3) * 2);
            }
            *(uint4*)(d + (size_t)n * K + tx2 * 8) = o.u;
        }
    }
}

// ==================================================================
// 128x128 grouped-GEMM core (proven ~820 TF): BK=64, 4 waves, single
// LDS buffer, stage -> sync -> 32 MFMA -> sync. T2 XOR swizzle via
// pre-swizzled global source (0 conflicts). T1 XCD-bijective grid.
// SWAPPED-OPERAND MFMA (bit-exact, r9/r10 forensics): lane holds 4
// column-consecutive outputs -> cvt_pk + 8B stores.
// ==================================================================

// ---------------- grouped GEMM 1 (+ fused w2 transpose tail blocks) ----------------

__global__ __launch_bounds__(256, 2) void gemm1_kernel(
    const u16* __restrict__ Xb, const u16* __restrict__ W1t,
    const float* __restrict__ b1, const int* __restrict__ sorted_rid,
    const int* __restrict__ tileE, const int* __restrict__ tileRow,
    const int* __restrict__ numTiles, u16* __restrict__ Hact,
    const float* __restrict__ w2, u16* __restrict__ w2t)
{
    __shared__ __align__(16) u16 SMEM[2 * 128 * 64];    // 32 KB
    int tid = threadIdx.x;
    int bid = blockIdx.x;

    if (bid >= G1_BLOCKS) {
        // ---- fused w2 transpose [E][FD][HD] -> [E][HD][FD], 256 threads
        char* ldsT = (char*)SMEM;                       // 128 rows x 32 slots x 8B
        int bb = bid - G1_BLOCKS;
        int e = bb >> 7; int r = bb & 127;              // 16 k-tiles x 8 n-tiles
        int n0 = (r & 7) * 128, k0 = (r >> 3) * 128;
        const int K = FD, N = HD;
        const float* s = w2 + (size_t)e * K * N + (size_t)k0 * N + n0;
        u16* d = w2t + (size_t)e * N * K + (size_t)n0 * K + k0;
        #pragma unroll
        for (int p = 0; p < 16; p++) {                  // 4096 float4 / 256 thr
            int idx = p * 256 + tid;
            int k = idx >> 5, tx = idx & 31;
            float4 v = *(const float4*)(s + (size_t)k * N + tx * 4);
            union { u16 q[4]; u64 u; } o;
            o.q[0] = f2bf(v.x); o.q[1] = f2bf(v.y); o.q[2] = f2bf(v.z); o.q[3] = f2bf(v.w);
            int phys = tx ^ (k & 31);
            *(u64*)(ldsT + k * 256 + phys * 8) = o.u;
        }
        __syncthreads();
        #pragma unroll
        for (int p = 0; p < 8; p++) {                   // 2048 uint4 / 256 thr
            int idx = p * 256 + tid;
            int n = idx >> 4, tx2 = idx & 15;
            union { u16 q[8]; uint4 u; } o;
            #pragma unroll
            for (int j = 0; j < 8; j++) {
                int k = tx2 * 8 + j;
                int phys = (n >> 2) ^ (k & 31);
                o.q[j] = *(const u16*)(ldsT + k * 256 + phys * 8 + (n & 3) * 2);
            }
            *(uint4*)(d + (size_t)n * K + tx2 * 8) = o.u;
        }
        return;
    }

    int xcd = bid & 7, slot = bid >> 3;
    int mt = xcd + (slot / NTN1) * 8;
    int n0 = (slot % NTN1) * 128;
    if (mt >= *numTiles) return;
    int e = tileE[mt];
    int row0 = tileRow[mt];

    int wave = tid >> 6, lane = tid & 63;
    int laneR = lane & 15, kgrp = lane >> 4;

    const u16* gA[4]; const u16* gB[4];
    #pragma unroll
    for (int i = 0; i < 4; i++) {
        int c = i * 256 + tid;
        int r = c >> 3, kc = c & 7;
        int kcs = kc ^ (r & 7);
        int rid = sorted_rid[row0 + r];
        int tok = rid < 0 ? 0 : (rid >> 1);
        gA[i] = Xb + (size_t)tok * HD + kcs * 8;
        gB[i] = W1t + ((size_t)e * FD + (n0 + r)) * HD + kcs * 8;
    }
    char* AsB = (char*)SMEM;
    char* BsB = (char*)(SMEM + 128 * 64);

    f32x4 acc[4][4] = {};

    int wr = wave >> 1, wc = wave & 1;
    int off0 = ((kgrp ^ (lane & 7)) << 4);
    int off1 = off0 ^ 64;
    const char* Abase = AsB + (wr * 64 + laneR) * 128;
    const char* Bbase = BsB + (wc * 64 + laneR) * 128;

    for (int kt = 0; kt < HD / 64; kt++) {
        #pragma unroll
        for (int i = 0; i < 4; i++)
            GLOAD16(gA[i], AsB + i * 4096 + wave * 1024);
        #pragma unroll
        for (int i = 0; i < 4; i++)
            GLOAD16(gB[i], BsB + i * 4096 + wave * 1024);
        #pragma unroll
        for (int i = 0; i < 4; i++) { gA[i] += 64; gB[i] += 64; }
        __syncthreads();
        #pragma unroll
        for (int kk = 0; kk < 2; kk++) {
            int off = kk ? off1 : off0;
            bf16x8 a[4], b[4];
            #pragma unroll
            for (int m = 0; m < 4; m++) a[m] = *(const bf16x8*)(Abase + m * 2048 + off);
            #pragma unroll
            for (int n = 0; n < 4; n++) b[n] = *(const bf16x8*)(Bbase + n * 2048 + off);
            #pragma unroll
            for (int m = 0; m < 4; m++)
                #pragma unroll
                for (int n = 0; n < 4; n++)
                    acc[m][n] = __builtin_amdgcn_mfma_f32_16x16x32_bf16(b[n], a[m], acc[m][n], 0, 0, 0);
        }
        __syncthreads();
    }

    // epilogue (swapped layout): bias float4 + gelu + cvt_pk + 8B stores
    const float* b1e = b1 + e * FD + n0;
    #pragma unroll
    for (int mf = 0; mf < 4; mf++) {
        int grow = row0 + wr * 64 + mf * 16 + laneR;
        u16* hrow = Hact + (size_t)grow * FD + n0;
        #pragma unroll
        for (int nf = 0; nf < 4; nf++) {
            int c = wc * 64 + nf * 16 + kgrp * 4;
            float4 bb = *(const float4*)(b1e + c);
            float g0 = gelu_f(acc[mf][nf][0] + bb.x);
            float g1 = gelu_f(acc[mf][nf][1] + bb.y);
            float g2 = gelu_f(acc[mf][nf][2] + bb.z);
            float g3 = gelu_f(acc[mf][nf][3] + bb.w);
            uint2 p = make_uint2(pk_bf16(g0, g1), pk_bf16(g2, g3));
            *(uint2*)(hrow + c) = p;
        }
    }
}

// ---------------- grouped GEMM 2: Out2[cslot] = H_act @ w2 + b2 (bf16, compacted) ----------------

__global__ __launch_bounds__(256, 2) void gemm2_kernel(
    const u16* __restrict__ Hact, const u16* __restrict__ W2t,
    const float* __restrict__ b2, const int* __restrict__ sorted_rid,
    const int* __restrict__ padcum,
    const int* __restrict__ tileE, const int* __restrict__ tileRow,
    const int* __restrict__ numTiles, u16* __restrict__ Out2)
{
    int bid = blockIdx.x;
    int xcd = bid & 7, slot = bid >> 3;
    int mt = xcd + (slot / NTN2) * 8;
    int n0 = (slot % NTN2) * 128;
    if (mt >= *numTiles) return;
    int e = tileE[mt];
    int row0 = tileRow[mt];

    __shared__ __align__(16) u16 As[128 * 64];
    __shared__ __align__(16) u16 Bs[128 * 64];

    int tid = threadIdx.x;
    int wave = tid >> 6, lane = tid & 63;
    int laneR = lane & 15, kgrp = lane >> 4;

    const u16* gA[4]; const u16* gB[4];
    #pragma unroll
    for (int i = 0; i < 4; i++) {
        int c = i * 256 + tid;
        int r = c >> 3, kc = c & 7;
        int kcs = kc ^ (r & 7);
        gA[i] = Hact + (size_t)(row0 + r) * FD + kcs * 8;
        gB[i] = W2t + ((size_t)e * HD + (n0 + r)) * FD + kcs * 8;
    }
    char* AsB = (char*)As; char* BsB = (char*)Bs;

    f32x4 acc[4][4] = {};

    int wr = wave >> 1, wc = wave & 1;
    int off0 = ((kgrp ^ (lane & 7)) << 4);
    int off1 = off0 ^ 64;
    const char* Abase = AsB + (wr * 64 + laneR) * 128;
    const char* Bbase = BsB + (wc * 64 + laneR) * 128;

    for (int kt = 0; kt < FD / 64; kt++) {
        #pragma unroll
        for (int i = 0; i < 4; i++)
            GLOAD16(gA[i], AsB + i * 4096 + wave * 1024);
        #pragma unroll
        for (int i = 0; i < 4; i++)
            GLOAD16(gB[i], BsB + i * 4096 + wave * 1024);
        #pragma unroll
        for (int i = 0; i < 4; i++) { gA[i] += 64; gB[i] += 64; }
        __syncthreads();
        #pragma unroll
        for (int kk = 0; kk < 2; kk++) {
            int off = kk ? off1 : off0;
            bf16x8 a[4], b[4];
            #pragma unroll
            for (int m = 0; m < 4; m++) a[m] = *(const bf16x8*)(Abase + m * 2048 + off);
            #pragma unroll
            for (int n = 0; n < 4; n++) b[n] = *(const bf16x8*)(Bbase + n * 2048 + off);
            #pragma unroll
            for (int m = 0; m < 4; m++)
                #pragma unroll
                for (int n = 0; n < 4; n++)
                    acc[m][n] = __builtin_amdgcn_mfma_f32_16x16x32_bf16(b[n], a[m], acc[m][n], 0, 0, 0);
        }
        __syncthreads();
    }

    // epilogue (swapped layout): 1 rid lookup per mf; cvt_pk + 8B stores
    const float* b2e = b2 + e * HD + n0;
    int pc = padcum[e];
    #pragma unroll
    for (int mf = 0; mf < 4; mf++) {
        int rr = row0 + wr * 64 + mf * 16 + laneR;
        int rid = sorted_rid[rr];
        if (rid < 0) continue;               // padding row: no storage
        u16* orow = Out2 + (size_t)(rr - pc) * HD + n0;
        #pragma unroll
        for (int nf = 0; nf < 4; nf++) {
            int c = wc * 64 + nf * 16 + kgrp * 4;
            float4 bb = *(const float4*)(b2e + c);
            float v0 = acc[mf][nf][0] + bb.x;
            float v1 = acc[mf][nf][1] + bb.y;
            float v2 = acc[mf][nf][2] + bb.z;
            float v3 = acc[mf][nf][3] + bb.w;
            uint2 p = make_uint2(pk_bf16(v0, v1), pk_bf16(v2, v3));
            *(uint2*)(orow + c) = p;
        }
    }
}

// ---------------- combine: y[t] = w0*Out2[inv[2t]] + w1*Out2[inv[2t+1]] ----------------

__global__ void combine_kernel(const u16* __restrict__ Out2, const int* __restrict__ inv,
                               const float* __restrict__ ew, float* __restrict__ y) {
    int i = blockIdx.x * blockDim.x + threadIdx.x;   // one thread = 8 cols of one token
    int tok = i >> 7;
    int c0 = (i & 127) << 3;
    int s0 = inv[2 * tok], s1 = inv[2 * tok + 1];
    float w0 = ew[2 * tok], w1 = ew[2 * tok + 1];
    union { uint4 v; u16 s[8]; } a, b;
    a.v = *(const uint4*)(Out2 + (size_t)s0 * HD + c0);
    b.v = *(const uint4*)(Out2 + (size_t)s1 * HD + c0);
    float out[8];
    #pragma unroll
    for (int j = 0; j < 8; j++) {
        union { u32 u; float f; } fa, fb;
        fa.u = (u32)a.s[j] << 16;
        fb.u = (u32)b.s[j] << 16;
        out[j] = w0 * fa.f + w1 * fb.f;
    }
    float4* yp = (float4*)(y + (size_t)tok * HD + c0);
    yp[0] = *(const float4*)&out[0];
    yp[1] = *(const float4*)&out[4];
}

// ---------------- launch ----------------

extern "C" void kernel_launch(void* const* d_in, const int* in_sizes, int n_in,
                              void* d_out, int out_size, void* d_ws, size_t ws_size,
                              hipStream_t stream) {
    const float* x  = (const float*)d_in[0];
    const float* ew = (const float*)d_in[1];
    const int*   te = (const int*)d_in[2];
    const float* w1 = (const float*)d_in[3];
    const float* b1 = (const float*)d_in[4];
    const float* w2 = (const float*)d_in[5];
    const float* b2 = (const float*)d_in[6];
    float* y = (float*)d_out;

    char* ws = (char*)d_ws;
    // Xb[0,32M) W1t[32M,64M) W2t[64M,96M) Hact[96M,228M) ip[228M+]
    // Out2 (compacted, 32768 x 1024 bf16 = 64MB) overlays Xb+W1t.
    u16* Xb   = (u16*)(ws);                      // 33,554,432 B
    u16* W1t  = (u16*)(ws + 33554432);           // 33,554,432 B
    u16* Out2 = (u16*)(ws);                      // 67,108,864 B (overlay)
    u16* W2t  = (u16*)(ws + 67108864);           // 33,554,432 B
    u16* Hact = (u16*)(ws + 100663296);          // 138,412,032 B (RP_MAX x 2048 bf16)
    char* ip  = ws + 239075328;
    int* numTiles = (int*)(ip);
    int* padcum   = (int*)(ip + 64);
    int* tileE    = (int*)(ip + 128);            // 1056 B
    int* tileRow  = (int*)(ip + 2048);           // 1056 B
    int* sorted   = (int*)(ip + 4096);           // 135,168 B
    int* inv      = (int*)(ip + 139264);         // 131,072 B

    // fused prep: routing (bid 0, overlaps) | convert_x | w1^T
    mega_prep<<<NB_PREP, 1024, 0, stream>>>(
        x, Xb, w1, W1t, te, sorted, inv, tileE, tileRow, numTiles, padcum);

    // grouped GEMM 1 + fused w2^T tail blocks
    gemm1_kernel<<<G1_BLOCKS + NB_W2, 256, 0, stream>>>(
        Xb, W1t, b1, sorted, tileE, tileRow, numTiles, Hact, w2, W2t);

    // grouped GEMM 2 (compacted plain stores)
    gemm2_kernel<<<MAX_MT * NTN2, 256, 0, stream>>>(
        Hact, W2t, b2, sorted, padcum, tileE, tileRow, numTiles, Out2);

    // weighted topk combine
    combine_kernel<<<(TOKENS * 128) / 256, 256, 0, stream>>>(Out2, inv, ew, y);
}

// Round 13
// 429.008 us; speedup vs baseline: 1.0406x; 1.0406x over previous
//
#include <hip/hip_runtime.h>
#include <hip/hip_bf16.h>
#include <math.h>

// Problem constants (B=4, S=4096 -> T=16384 tokens)
#define TOKENS 16384
#define HD 1024
#define FD 2048
#define NEXP 8
#define RP_MAX (264 * 128)   // max padded routed rows
#define MAX_MT 264           // max 128-row m-tiles (divisible by 8 for XCD swizzle)
#define MTL_MAX 33           // m-tiles per XCD (MAX_MT/8)
#define QG 9                 // ceil(MTL_MAX/4) mt-quads per XCD
#define NTN1 16              // gemm1 n-tiles: FD/128
#define NTN2 8               // gemm2 n-tiles: HD/128
#define G1_BLOCKS (8 * QG * 4 * NTN1)   // 4608
#define G2_BLOCKS (8 * QG * 4 * NTN2)   // 2304

// mega-prep block ranges (1024 threads/block): routing FIRST (overlaps)
#define NB_CONV 2048
#define NB_W1   1024
#define NB_W2   1024
#define NB_PREP (1 + NB_CONV + NB_W1 + NB_W2)

typedef __bf16 bf16x8 __attribute__((ext_vector_type(8)));
typedef float f32x4 __attribute__((ext_vector_type(4)));
typedef unsigned short u16;
typedef unsigned int u32;
typedef unsigned long long u64;

__device__ __forceinline__ u16 f2bf(float f) {
    union { float f; u32 u; } v; v.f = f;
    return (u16)((v.u + 0x7FFFu + ((v.u >> 16) & 1u)) >> 16);
}

// pack two f32 -> two bf16 in one instruction (lo = src0, hi = src1)
__device__ __forceinline__ u32 pk_bf16(float lo, float hi) {
    u32 p;
    asm("v_cvt_pk_bf16_f32 %0, %1, %2" : "=v"(p) : "v"(lo), "v"(hi));
    return p;
}

// gelu tanh/sigmoid form: v * sigmoid(1.5957692*(v + 0.044715 v^3))
__device__ __forceinline__ float gelu_f(float v) {
    float u = __builtin_fmaf(0.044715f * v * v, v, v);   // v + 0.044715 v^3
    float ez = __builtin_amdgcn_exp2f(-2.302208f * u);   // exp(-1.5957692 u)
    return v * __builtin_amdgcn_rcpf(1.0f + ez);
}

#define GLOAD16(g, l) __builtin_amdgcn_global_load_lds( \
    (const __attribute__((address_space(1))) u32*)(g),  \
    (__attribute__((address_space(3))) u32*)(l), 16, 0, 0)

// ==================================================================
// mega-prep: routing (bid 0, overlaps) | convert_x | w1^T | w2^T
// ==================================================================
__global__ __launch_bounds__(1024) void mega_prep(
    const float* __restrict__ x, u16* __restrict__ xb,
    const float* __restrict__ w1, u16* __restrict__ w1t,
    const float* __restrict__ w2, u16* __restrict__ w2t,
    const int* __restrict__ te,
    int* sorted_rid, int* inv, int* tileE, int* tileRow,
    int* numTiles, int* padcum)
{
    __shared__ __align__(16) char ldsT[32768];          // 128 rows x 32 slots x 8B
    __shared__ int cntS[NEXP], offsS[NEXP], fillS[NEXP], padS[NEXP], ntS;
    int b = blockIdx.x;
    int tid = threadIdx.x;

    if (b == 0) {
        // ---- routing (single block, runs concurrently with blocks below)
        int lane = tid & 63;
        if (tid < NEXP) cntS[tid] = 0;
        __syncthreads();
        int h[NEXP] = {0, 0, 0, 0, 0, 0, 0, 0};
        for (int j = tid; j < TOKENS * 2; j += 1024) {
            int v = te[j];
            #pragma unroll
            for (int e = 0; e < NEXP; e++) h[e] += (v == e);
        }
        #pragma unroll
        for (int e = 0; e < NEXP; e++) {
            int s = h[e];
            #pragma unroll
            for (int o = 32; o > 0; o >>= 1) s += __shfl_down(s, o, 64);
            if (lane == 0 && s) atomicAdd(&cntS[e], s);
        }
        __syncthreads();
        if (tid == 0) {
            int o = 0, t = 0, pc = 0;
            for (int e = 0; e < NEXP; e++) {
                offsS[e] = o; fillS[e] = 0;
                int pad = o - pc;
                padS[e] = pad; padcum[e] = pad;
                int c = cntS[e];
                int nt = (c + 127) >> 7;
                for (int i = 0; i < nt; i++) { tileE[t] = e; tileRow[t] = o + i * 128; t++; }
                o += nt * 128; pc += c;
            }
            ntS = t;
            *numTiles = t;
        }
        __syncthreads();
        int tot = ntS * 128;
        for (int i = tid; i < tot; i += 1024) sorted_rid[i] = -1;
        __syncthreads();
        for (int j = tid; j < TOKENS * 2; j += 1024) {   // full waves always
            int v = te[j];
            int base = 0;
            #pragma unroll
            for (int e = 0; e < NEXP; e++) {
                unsigned long long m = __ballot(v == e);
                if (m) {
                    int ldr = (int)__builtin_ctzll(m);
                    int bb = 0;
                    if (lane == ldr) bb = atomicAdd(&fillS[e], __popcll(m));
                    bb = __shfl(bb, ldr, 64);
                    if (v == e) base = bb + (int)__popcll(m & ((1ull << lane) - 1ull));
                }
            }
            int p = offsS[v] + base;
            sorted_rid[p] = j;
            inv[j] = p - padS[v];            // compacted (pad-free) slot
        }
        return;
    }
    if (b <= NB_CONV) {                      // ---- convert x -> bf16
        int i = (b - 1) * 1024 + tid;        // one thread = 8 elems
        const float4* xv = (const float4*)x;
        float4 a = xv[i * 2], c = xv[i * 2 + 1];
        union { u16 s[8]; uint4 v; } o;
        o.s[0] = f2bf(a.x); o.s[1] = f2bf(a.y); o.s[2] = f2bf(a.z); o.s[3] = f2bf(a.w);
        o.s[4] = f2bf(c.x); o.s[5] = f2bf(c.y); o.s[6] = f2bf(c.z); o.s[7] = f2bf(c.w);
        *(uint4*)(xb + (size_t)i * 8) = o.v;
        return;
    }
    // ---- weight transpose [E][K][N] -> [E][N][K], 128x128 tiles
    {
        const float* src; u16* dst; int K, N, n0, k0, e;
        if (b <= NB_CONV + NB_W1) {
            int bb = b - 1 - NB_CONV;
            e = bb >> 7; int r = bb & 127;   // 8 k-tiles x 16 n-tiles
            n0 = (r & 15) * 128; k0 = (r >> 4) * 128;
            K = HD; N = FD; src = w1; dst = w1t;
        } else {
            int bb = b - 1 - NB_CONV - NB_W1;
            e = bb >> 7; int r = bb & 127;   // 16 k-tiles x 8 n-tiles
            n0 = (r & 7) * 128; k0 = (r >> 3) * 128;
            K = FD; N = HD; src = w2; dst = w2t;
        }
        const float* s = src + (size_t)e * K * N + (size_t)k0 * N + n0;
        u16* d = dst + (size_t)e * N * K + (size_t)n0 * K + k0;
        int tx = tid & 31, ty = tid >> 5;
        #pragma unroll
        for (int p = 0; p < 4; p++) {
            int k = p * 32 + ty;
            float4 v = *(const float4*)(s + (size_t)k * N + tx * 4);
            union { u16 q[4]; u64 u; } o;
            o.q[0] = f2bf(v.x); o.q[1] = f2bf(v.y); o.q[2] = f2bf(v.z); o.q[3] = f2bf(v.w);
            int phys = tx ^ (k & 31);
            *(u64*)(ldsT + k * 256 + phys * 8) = o.u;
        }
        __syncthreads();
        int tx2 = tid & 15, ty2 = tid >> 4;
        #pragma unroll
        for (int p = 0; p < 2; p++) {
            int n = p * 64 + ty2;
            union { u16 q[8]; uint4 u; } o;
            #pragma unroll
            for (int j = 0; j < 8; j++) {
                int k = tx2 * 8 + j;
                int phys = (n >> 2) ^ (k & 31);
                o.q[j] = *(const u16*)(ldsT + k * 256 + phys * 8 + (n & 3) * 2);
            }
            *(uint4*)(d + (size_t)n * K + tx2 * 8) = o.u;
        }
    }
}

// ==================================================================
// 128x128 grouped-GEMM core (proven ~820 TF): BK=64, 4 waves, single
// LDS buffer, stage -> sync -> 32 MFMA -> sync. T2 XOR swizzle via
// pre-swizzled global source (0 conflicts). T1 XCD-bijective grid +
// mt-QUAD decode: 4 m-tiles share each B-panel epoch (L2 reuse;
// working set 4 A-panels + 1 B-panel ~1.25MB < 4MB per-XCD L2).
// SWAPPED-OPERAND MFMA (bit-exact): lane holds 4 column-consecutive
// outputs -> cvt_pk + 8B stores.
// ==================================================================

// ---------------- grouped GEMM 1: H_act = gelu(X[gather] @ w1 + b1) ----------------

__global__ __launch_bounds__(256, 2) void gemm1_kernel(
    const u16* __restrict__ Xb, const u16* __restrict__ W1t,
    const float* __restrict__ b1, const int* __restrict__ sorted_rid,
    const int* __restrict__ tileE, const int* __restrict__ tileRow,
    const int* __restrict__ numTiles, u16* __restrict__ Hact)
{
    int bid = blockIdx.x;
    int xcd = bid & 7, slot = bid >> 3;      // slot 0..575
    int grp = slot >> 6, rem = slot & 63;    // 4 mt x 16 nt per group
    int mtl = grp * 4 + (rem & 3);
    int n0 = (rem >> 2) * 128;
    int mt = xcd + mtl * 8;
    if (mt >= *numTiles) return;
    int e = tileE[mt];
    int row0 = tileRow[mt];

    __shared__ __align__(16) u16 As[128 * 64];
    __shared__ __align__(16) u16 Bs[128 * 64];

    int tid = threadIdx.x;
    int wave = tid >> 6, lane = tid & 63;
    int laneR = lane & 15, kgrp = lane >> 4;

    const u16* gA[4]; const u16* gB[4];
    #pragma unroll
    for (int i = 0; i < 4; i++) {
        int c = i * 256 + tid;
        int r = c >> 3, kc = c & 7;
        int kcs = kc ^ (r & 7);
        int rid = sorted_rid[row0 + r];
        int tok = rid < 0 ? 0 : (rid >> 1);
        gA[i] = Xb + (size_t)tok * HD + kcs * 8;
        gB[i] = W1t + ((size_t)e * FD + (n0 + r)) * HD + kcs * 8;
    }
    char* AsB = (char*)As; char* BsB = (char*)Bs;

    f32x4 acc[4][4] = {};

    int wr = wave >> 1, wc = wave & 1;
    int off0 = ((kgrp ^ (lane & 7)) << 4);
    int off1 = off0 ^ 64;
    const char* Abase = AsB + (wr * 64 + laneR) * 128;
    const char* Bbase = BsB + (wc * 64 + laneR) * 128;

    for (int kt = 0; kt < HD / 64; kt++) {
        #pragma unroll
        for (int i = 0; i < 4; i++)
            GLOAD16(gA[i], AsB + i * 4096 + wave * 1024);
        #pragma unroll
        for (int i = 0; i < 4; i++)
            GLOAD16(gB[i], BsB + i * 4096 + wave * 1024);
        #pragma unroll
        for (int i = 0; i < 4; i++) { gA[i] += 64; gB[i] += 64; }
        __syncthreads();
        #pragma unroll
        for (int kk = 0; kk < 2; kk++) {
            int off = kk ? off1 : off0;
            bf16x8 a[4], b[4];
            #pragma unroll
            for (int m = 0; m < 4; m++) a[m] = *(const bf16x8*)(Abase + m * 2048 + off);
            #pragma unroll
            for (int n = 0; n < 4; n++) b[n] = *(const bf16x8*)(Bbase + n * 2048 + off);
            #pragma unroll
            for (int m = 0; m < 4; m++)
                #pragma unroll
                for (int n = 0; n < 4; n++)
                    acc[m][n] = __builtin_amdgcn_mfma_f32_16x16x32_bf16(b[n], a[m], acc[m][n], 0, 0, 0);
        }
        __syncthreads();
    }

    // epilogue (swapped layout): bias float4 + gelu + cvt_pk + 8B stores
    const float* b1e = b1 + e * FD + n0;
    #pragma unroll
    for (int mf = 0; mf < 4; mf++) {
        int grow = row0 + wr * 64 + mf * 16 + laneR;
        u16* hrow = Hact + (size_t)grow * FD + n0;
        #pragma unroll
        for (int nf = 0; nf < 4; nf++) {
            int c = wc * 64 + nf * 16 + kgrp * 4;
            float4 bb = *(const float4*)(b1e + c);
            float g0 = gelu_f(acc[mf][nf][0] + bb.x);
            float g1 = gelu_f(acc[mf][nf][1] + bb.y);
            float g2 = gelu_f(acc[mf][nf][2] + bb.z);
            float g3 = gelu_f(acc[mf][nf][3] + bb.w);
            uint2 p = make_uint2(pk_bf16(g0, g1), pk_bf16(g2, g3));
            *(uint2*)(hrow + c) = p;
        }
    }
}

// ---------------- grouped GEMM 2: Out2[cslot] = H_act @ w2 + b2 (bf16, compacted) ----------------

__global__ __launch_bounds__(256, 2) void gemm2_kernel(
    const u16* __restrict__ Hact, const u16* __restrict__ W2t,
    const float* __restrict__ b2, const int* __restrict__ sorted_rid,
    const int* __restrict__ padcum,
    const int* __restrict__ tileE, const int* __restrict__ tileRow,
    const int* __restrict__ numTiles, u16* __restrict__ Out2)
{
    int bid = blockIdx.x;
    int xcd = bid & 7, slot = bid >> 3;      // slot 0..287
    int grp = slot >> 5, rem = slot & 31;    // 4 mt x 8 nt per group
    int mtl = grp * 4 + (rem & 3);
    int n0 = (rem >> 2) * 128;
    int mt = xcd + mtl * 8;
    if (mt >= *numTiles) return;
    int e = tileE[mt];
    int row0 = tileRow[mt];

    __shared__ __align__(16) u16 As[128 * 64];
    __shared__ __align__(16) u16 Bs[128 * 64];

    int tid = threadIdx.x;
    int wave = tid >> 6, lane = tid & 63;
    int laneR = lane & 15, kgrp = lane >> 4;

    const u16* gA[4]; const u16* gB[4];
    #pragma unroll
    for (int i = 0; i < 4; i++) {
        int c = i * 256 + tid;
        int r = c >> 3, kc = c & 7;
        int kcs = kc ^ (r & 7);
        gA[i] = Hact + (size_t)(row0 + r) * FD + kcs * 8;
        gB[i] = W2t + ((size_t)e * HD + (n0 + r)) * FD + kcs * 8;
    }
    char* AsB = (char*)As; char* BsB = (char*)Bs;

    f32x4 acc[4][4] = {};

    int wr = wave >> 1, wc = wave & 1;
    int off0 = ((kgrp ^ (lane & 7)) << 4);
    int off1 = off0 ^ 64;
    const char* Abase = AsB + (wr * 64 + laneR) * 128;
    const char* Bbase = BsB + (wc * 64 + laneR) * 128;

    for (int kt = 0; kt < FD / 64; kt++) {
        #pragma unroll
        for (int i = 0; i < 4; i++)
            GLOAD16(gA[i], AsB + i * 4096 + wave * 1024);
        #pragma unroll
        for (int i = 0; i < 4; i++)
            GLOAD16(gB[i], BsB + i * 4096 + wave * 1024);
        #pragma unroll
        for (int i = 0; i < 4; i++) { gA[i] += 64; gB[i] += 64; }
        __syncthreads();
        #pragma unroll
        for (int kk = 0; kk < 2; kk++) {
            int off = kk ? off1 : off0;
            bf16x8 a[4], b[4];
            #pragma unroll
            for (int m = 0; m < 4; m++) a[m] = *(const bf16x8*)(Abase + m * 2048 + off);
            #pragma unroll
            for (int n = 0; n < 4; n++) b[n] = *(const bf16x8*)(Bbase + n * 2048 + off);
            #pragma unroll
            for (int m = 0; m < 4; m++)
                #pragma unroll
                for (int n = 0; n < 4; n++)
                    acc[m][n] = __builtin_amdgcn_mfma_f32_16x16x32_bf16(b[n], a[m], acc[m][n], 0, 0, 0);
        }
        __syncthreads();
    }

    // epilogue (swapped layout): 1 rid lookup per mf; cvt_pk + 8B stores
    const float* b2e = b2 + e * HD + n0;
    int pc = padcum[e];
    #pragma unroll
    for (int mf = 0; mf < 4; mf++) {
        int rr = row0 + wr * 64 + mf * 16 + laneR;
        int rid = sorted_rid[rr];
        if (rid < 0) continue;               // padding row: no storage
        u16* orow = Out2 + (size_t)(rr - pc) * HD + n0;
        #pragma unroll
        for (int nf = 0; nf < 4; nf++) {
            int c = wc * 64 + nf * 16 + kgrp * 4;
            float4 bb = *(const float4*)(b2e + c);
            float v0 = acc[mf][nf][0] + bb.x;
            float v1 = acc[mf][nf][1] + bb.y;
            float v2 = acc[mf][nf][2] + bb.z;
            float v3 = acc[mf][nf][3] + bb.w;
            uint2 p = make_uint2(pk_bf16(v0, v1), pk_bf16(v2, v3));
            *(uint2*)(orow + c) = p;
        }
    }
}

// ---------------- combine: y[t] = w0*Out2[inv[2t]] + w1*Out2[inv[2t+1]] ----------------

__global__ void combine_kernel(const u16* __restrict__ Out2, const int* __restrict__ inv,
                               const float* __restrict__ ew, float* __restrict__ y) {
    int i = blockIdx.x * blockDim.x + threadIdx.x;   // one thread = 8 cols of one token
    int tok = i >> 7;
    int c0 = (i & 127) << 3;
    int s0 = inv[2 * tok], s1 = inv[2 * tok + 1];
    float w0 = ew[2 * tok], w1 = ew[2 * tok + 1];
    union { uint4 v; u16 s[8]; } a, b;
    a.v = *(const uint4*)(Out2 + (size_t)s0 * HD + c0);
    b.v = *(const uint4*)(Out2 + (size_t)s1 * HD + c0);
    float out[8];
    #pragma unroll
    for (int j = 0; j < 8; j++) {
        union { u32 u; float f; } fa, fb;
        fa.u = (u32)a.s[j] << 16;
        fb.u = (u32)b.s[j] << 16;
        out[j] = w0 * fa.f + w1 * fb.f;
    }
    float4* yp = (float4*)(y + (size_t)tok * HD + c0);
    yp[0] = *(const float4*)&out[0];
    yp[1] = *(const float4*)&out[4];
}

// ---------------- launch ----------------

extern "C" void kernel_launch(void* const* d_in, const int* in_sizes, int n_in,
                              void* d_out, int out_size, void* d_ws, size_t ws_size,
                              hipStream_t stream) {
    const float* x  = (const float*)d_in[0];
    const float* ew = (const float*)d_in[1];
    const int*   te = (const int*)d_in[2];
    const float* w1 = (const float*)d_in[3];
    const float* b1 = (const float*)d_in[4];
    const float* w2 = (const float*)d_in[5];
    const float* b2 = (const float*)d_in[6];
    float* y = (float*)d_out;

    char* ws = (char*)d_ws;
    // Xb[0,32M) W1t[32M,64M) W2t[64M,96M) Hact[96M,228M) ip[228M+]
    // Out2 (compacted, 32768 x 1024 bf16 = 64MB) overlays Xb+W1t.
    u16* Xb   = (u16*)(ws);                      // 33,554,432 B
    u16* W1t  = (u16*)(ws + 33554432);           // 33,554,432 B
    u16* Out2 = (u16*)(ws);                      // 67,108,864 B (overlay)
    u16* W2t  = (u16*)(ws + 67108864);           // 33,554,432 B
    u16* Hact = (u16*)(ws + 100663296);          // 138,412,032 B (RP_MAX x 2048 bf16)
    char* ip  = ws + 239075328;
    int* numTiles = (int*)(ip);
    int* padcum   = (int*)(ip + 64);
    int* tileE    = (int*)(ip + 128);            // 1056 B
    int* tileRow  = (int*)(ip + 2048);           // 1056 B
    int* sorted   = (int*)(ip + 4096);           // 135,168 B
    int* inv      = (int*)(ip + 139264);         // 131,072 B

    // fused prep: routing (bid 0, overlaps) | convert_x | w1^T | w2^T
    mega_prep<<<NB_PREP, 1024, 0, stream>>>(
        x, Xb, w1, W1t, w2, W2t, te, sorted, inv, tileE, tileRow, numTiles, padcum);

    // grouped GEMM 1 (mt-quad L2-reuse decode)
    gemm1_kernel<<<G1_BLOCKS, 256, 0, stream>>>(
        Xb, W1t, b1, sorted, tileE, tileRow, numTiles, Hact);

    // grouped GEMM 2 (compacted plain stores, mt-quad decode)
    gemm2_kernel<<<G2_BLOCKS, 256, 0, stream>>>(
        Hact, W2t, b2, sorted, padcum, tileE, tileRow, numTiles, Out2);

    // weighted topk combine
    combine_kernel<<<(TOKENS * 128) / 256, 256, 0, stream>>>(Out2, inv, ew, y);
}

// Round 14
// 424.046 us; speedup vs baseline: 1.0528x; 1.0117x over previous
//
#include <hip/hip_runtime.h>
#include <hip/hip_bf16.h>
#include <math.h>

// Problem constants (B=4, S=4096 -> T=16384 tokens)
#define TOKENS 16384
#define HD 1024
#define FD 2048
#define NEXP 8
#define RP_MAX (264 * 128)   // max padded routed rows
#define MAX_MT 264           // max 128-row m-tiles (divisible by 8 for XCD swizzle)
#define MTL_MAX 33           // m-tiles per XCD (MAX_MT/8)
#define QG 9                 // ceil(MTL_MAX/4) mt-quads per XCD
#define NTN1 16              // gemm1 n-tiles: FD/128
#define NTN2 8               // gemm2 n-tiles: HD/128
#define G1_BLOCKS (MAX_MT * NTN1)       // 4224 (nt-fast decode)
#define G2_BLOCKS (8 * QG * 4 * NTN2)   // 2304 (mt-quad decode)

// mega-prep block ranges (1024 threads/block): routing FIRST (overlaps)
#define NB_CONV 2048
#define NB_W1   1024
#define NB_W2   1024
#define NB_PREP (1 + NB_CONV + NB_W1 + NB_W2)

typedef __bf16 bf16x8 __attribute__((ext_vector_type(8)));
typedef float f32x4 __attribute__((ext_vector_type(4)));
typedef unsigned short u16;
typedef unsigned int u32;
typedef unsigned long long u64;

__device__ __forceinline__ u16 f2bf(float f) {
    union { float f; u32 u; } v; v.f = f;
    return (u16)((v.u + 0x7FFFu + ((v.u >> 16) & 1u)) >> 16);
}

// pack two f32 -> two bf16 in one instruction (lo = src0, hi = src1)
__device__ __forceinline__ u32 pk_bf16(float lo, float hi) {
    u32 p;
    asm("v_cvt_pk_bf16_f32 %0, %1, %2" : "=v"(p) : "v"(lo), "v"(hi));
    return p;
}

// gelu tanh/sigmoid form: v * sigmoid(1.5957692*(v + 0.044715 v^3))
__device__ __forceinline__ float gelu_f(float v) {
    float u = __builtin_fmaf(0.044715f * v * v, v, v);   // v + 0.044715 v^3
    float ez = __builtin_amdgcn_exp2f(-2.302208f * u);   // exp(-1.5957692 u)
    return v * __builtin_amdgcn_rcpf(1.0f + ez);
}

#define GLOAD16(g, l) __builtin_amdgcn_global_load_lds( \
    (const __attribute__((address_space(1))) u32*)(g),  \
    (__attribute__((address_space(3))) u32*)(l), 16, 0, 0)

// ==================================================================
// mega-prep: routing (bid 0, overlaps) | convert_x | w1^T | w2^T
// ==================================================================
__global__ __launch_bounds__(1024) void mega_prep(
    const float* __restrict__ x, u16* __restrict__ xb,
    const float* __restrict__ w1, u16* __restrict__ w1t,
    const float* __restrict__ w2, u16* __restrict__ w2t,
    const int* __restrict__ te,
    int* sorted_rid, int* inv, int* tileE, int* tileRow,
    int* numTiles, int* padcum)
{
    __shared__ __align__(16) char ldsT[32768];          // 128 rows x 32 slots x 8B
    __shared__ int cntS[NEXP], offsS[NEXP], fillS[NEXP], padS[NEXP], ntS;
    int b = blockIdx.x;
    int tid = threadIdx.x;

    if (b == 0) {
        // ---- routing (single block, runs concurrently with blocks below)
        int lane = tid & 63;
        if (tid < NEXP) cntS[tid] = 0;
        __syncthreads();
        int h[NEXP] = {0, 0, 0, 0, 0, 0, 0, 0};
        for (int j = tid; j < TOKENS * 2; j += 1024) {
            int v = te[j];
            #pragma unroll
            for (int e = 0; e < NEXP; e++) h[e] += (v == e);
        }
        #pragma unroll
        for (int e = 0; e < NEXP; e++) {
            int s = h[e];
            #pragma unroll
            for (int o = 32; o > 0; o >>= 1) s += __shfl_down(s, o, 64);
            if (lane == 0 && s) atomicAdd(&cntS[e], s);
        }
        __syncthreads();
        if (tid == 0) {
            int o = 0, t = 0, pc = 0;
            for (int e = 0; e < NEXP; e++) {
                offsS[e] = o; fillS[e] = 0;
                int pad = o - pc;
                padS[e] = pad; padcum[e] = pad;
                int c = cntS[e];
                int nt = (c + 127) >> 7;
                for (int i = 0; i < nt; i++) { tileE[t] = e; tileRow[t] = o + i * 128; t++; }
                o += nt * 128; pc += c;
            }
            ntS = t;
            *numTiles = t;
        }
        __syncthreads();
        int tot = ntS * 128;
        for (int i = tid; i < tot; i += 1024) sorted_rid[i] = -1;
        __syncthreads();
        for (int j = tid; j < TOKENS * 2; j += 1024) {   // full waves always
            int v = te[j];
            int base = 0;
            #pragma unroll
            for (int e = 0; e < NEXP; e++) {
                unsigned long long m = __ballot(v == e);
                if (m) {
                    int ldr = (int)__builtin_ctzll(m);
                    int bb = 0;
                    if (lane == ldr) bb = atomicAdd(&fillS[e], __popcll(m));
                    bb = __shfl(bb, ldr, 64);
                    if (v == e) base = bb + (int)__popcll(m & ((1ull << lane) - 1ull));
                }
            }
            int p = offsS[v] + base;
            sorted_rid[p] = j;
            inv[j] = p - padS[v];            // compacted (pad-free) slot
        }
        return;
    }
    if (b <= NB_CONV) {                      // ---- convert x -> bf16
        int i = (b - 1) * 1024 + tid;        // one thread = 8 elems
        const float4* xv = (const float4*)x;
        float4 a = xv[i * 2], c = xv[i * 2 + 1];
        union { u16 s[8]; uint4 v; } o;
        o.s[0] = f2bf(a.x); o.s[1] = f2bf(a.y); o.s[2] = f2bf(a.z); o.s[3] = f2bf(a.w);
        o.s[4] = f2bf(c.x); o.s[5] = f2bf(c.y); o.s[6] = f2bf(c.z); o.s[7] = f2bf(c.w);
        *(uint4*)(xb + (size_t)i * 8) = o.v;
        return;
    }
    // ---- weight transpose [E][K][N] -> [E][N][K], 128x128 tiles
    {
        const float* src; u16* dst; int K, N, n0, k0, e;
        if (b <= NB_CONV + NB_W1) {
            int bb = b - 1 - NB_CONV;
            e = bb >> 7; int r = bb & 127;   // 8 k-tiles x 16 n-tiles
            n0 = (r & 15) * 128; k0 = (r >> 4) * 128;
            K = HD; N = FD; src = w1; dst = w1t;
        } else {
            int bb = b - 1 - NB_CONV - NB_W1;
            e = bb >> 7; int r = bb & 127;   // 16 k-tiles x 8 n-tiles
            n0 = (r & 7) * 128; k0 = (r >> 3) * 128;
            K = FD; N = HD; src = w2; dst = w2t;
        }
        const float* s = src + (size_t)e * K * N + (size_t)k0 * N + n0;
        u16* d = dst + (size_t)e * N * K + (size_t)n0 * K + k0;
        int tx = tid & 31, ty = tid >> 5;
        #pragma unroll
        for (int p = 0; p < 4; p++) {
            int k = p * 32 + ty;
            float4 v = *(const float4*)(s + (size_t)k * N + tx * 4);
            union { u16 q[4]; u64 u; } o;
            o.q[0] = f2bf(v.x); o.q[1] = f2bf(v.y); o.q[2] = f2bf(v.z); o.q[3] = f2bf(v.w);
            int phys = tx ^ (k & 31);
            *(u64*)(ldsT + k * 256 + phys * 8) = o.u;
        }
        __syncthreads();
        int tx2 = tid & 15, ty2 = tid >> 4;
        #pragma unroll
        for (int p = 0; p < 2; p++) {
            int n = p * 64 + ty2;
            union { u16 q[8]; uint4 u; } o;
            #pragma unroll
            for (int j = 0; j < 8; j++) {
                int k = tx2 * 8 + j;
                int phys = (n >> 2) ^ (k & 31);
                o.q[j] = *(const u16*)(ldsT + k * 256 + phys * 8 + (n & 3) * 2);
            }
            *(uint4*)(d + (size_t)n * K + tx2 * 8) = o.u;
        }
    }
}

// ==================================================================
// 128x128 grouped-GEMM core (proven ~820 TF): BK=64, 4 waves, single
// LDS buffer, stage -> sync -> 32 MFMA -> sync. T2 XOR swizzle via
// pre-swizzled global source (0 conflicts). T1 XCD-bijective grid.
// Decode specialization (r13 lesson): gemm1 = nt-fast (pins GATHERED
// A-panel in L2, streams B); gemm2 = mt-quad (shares B across 4
// contiguous-A m-tiles). SWAPPED-OPERAND MFMA (bit-exact): lane holds
// 4 column-consecutive outputs -> cvt_pk + 8B stores.
// ==================================================================

// ---------------- grouped GEMM 1: H_act = gelu(X[gather] @ w1 + b1) ----------------

__global__ __launch_bounds__(256, 2) void gemm1_kernel(
    const u16* __restrict__ Xb, const u16* __restrict__ W1t,
    const float* __restrict__ b1, const int* __restrict__ sorted_rid,
    const int* __restrict__ tileE, const int* __restrict__ tileRow,
    const int* __restrict__ numTiles, u16* __restrict__ Hact)
{
    // nt-fast XCD decode: consecutive slots on one XCD share mt (A-panel)
    int bid = blockIdx.x;
    int xcd = bid & 7, slot = bid >> 3;
    int mt = xcd + (slot / NTN1) * 8;
    int n0 = (slot % NTN1) * 128;
    if (mt >= *numTiles) return;
    int e = tileE[mt];
    int row0 = tileRow[mt];

    __shared__ __align__(16) u16 As[128 * 64];
    __shared__ __align__(16) u16 Bs[128 * 64];

    int tid = threadIdx.x;
    int wave = tid >> 6, lane = tid & 63;
    int laneR = lane & 15, kgrp = lane >> 4;

    const u16* gA[4]; const u16* gB[4];
    #pragma unroll
    for (int i = 0; i < 4; i++) {
        int c = i * 256 + tid;
        int r = c >> 3, kc = c & 7;
        int kcs = kc ^ (r & 7);
        int rid = sorted_rid[row0 + r];
        int tok = rid < 0 ? 0 : (rid >> 1);
        gA[i] = Xb + (size_t)tok * HD + kcs * 8;
        gB[i] = W1t + ((size_t)e * FD + (n0 + r)) * HD + kcs * 8;
    }
    char* AsB = (char*)As; char* BsB = (char*)Bs;

    f32x4 acc[4][4] = {};

    int wr = wave >> 1, wc = wave & 1;
    int off0 = ((kgrp ^ (lane & 7)) << 4);
    int off1 = off0 ^ 64;
    const char* Abase = AsB + (wr * 64 + laneR) * 128;
    const char* Bbase = BsB + (wc * 64 + laneR) * 128;

    for (int kt = 0; kt < HD / 64; kt++) {
        #pragma unroll
        for (int i = 0; i < 4; i++)
            GLOAD16(gA[i], AsB + i * 4096 + wave * 1024);
        #pragma unroll
        for (int i = 0; i < 4; i++)
            GLOAD16(gB[i], BsB + i * 4096 + wave * 1024);
        #pragma unroll
        for (int i = 0; i < 4; i++) { gA[i] += 64; gB[i] += 64; }
        __syncthreads();
        #pragma unroll
        for (int kk = 0; kk < 2; kk++) {
            int off = kk ? off1 : off0;
            bf16x8 a[4], b[4];
            #pragma unroll
            for (int m = 0; m < 4; m++) a[m] = *(const bf16x8*)(Abase + m * 2048 + off);
            #pragma unroll
            for (int n = 0; n < 4; n++) b[n] = *(const bf16x8*)(Bbase + n * 2048 + off);
            #pragma unroll
            for (int m = 0; m < 4; m++)
                #pragma unroll
                for (int n = 0; n < 4; n++)
                    acc[m][n] = __builtin_amdgcn_mfma_f32_16x16x32_bf16(b[n], a[m], acc[m][n], 0, 0, 0);
        }
        __syncthreads();
    }

    // epilogue (swapped layout): bias float4 + gelu + cvt_pk + 8B stores
    const float* b1e = b1 + e * FD + n0;
    #pragma unroll
    for (int mf = 0; mf < 4; mf++) {
        int grow = row0 + wr * 64 + mf * 16 + laneR;
        u16* hrow = Hact + (size_t)grow * FD + n0;
        #pragma unroll
        for (int nf = 0; nf < 4; nf++) {
            int c = wc * 64 + nf * 16 + kgrp * 4;
            float4 bb = *(const float4*)(b1e + c);
            float g0 = gelu_f(acc[mf][nf][0] + bb.x);
            float g1 = gelu_f(acc[mf][nf][1] + bb.y);
            float g2 = gelu_f(acc[mf][nf][2] + bb.z);
            float g3 = gelu_f(acc[mf][nf][3] + bb.w);
            uint2 p = make_uint2(pk_bf16(g0, g1), pk_bf16(g2, g3));
            *(uint2*)(hrow + c) = p;
        }
    }
}

// ---------------- grouped GEMM 2: Out2[cslot] = H_act @ w2 + b2 (bf16, compacted) ----------------

__global__ __launch_bounds__(256, 2) void gemm2_kernel(
    const u16* __restrict__ Hact, const u16* __restrict__ W2t,
    const float* __restrict__ b2, const int* __restrict__ sorted_rid,
    const int* __restrict__ padcum,
    const int* __restrict__ tileE, const int* __restrict__ tileRow,
    const int* __restrict__ numTiles, u16* __restrict__ Out2)
{
    // mt-quad decode: 4 m-tiles share each B-panel epoch (L2 reuse)
    int bid = blockIdx.x;
    int xcd = bid & 7, slot = bid >> 3;      // slot 0..287
    int grp = slot >> 5, rem = slot & 31;    // 4 mt x 8 nt per group
    int mtl = grp * 4 + (rem & 3);
    int n0 = (rem >> 2) * 128;
    int mt = xcd + mtl * 8;
    if (mt >= *numTiles) return;
    int e = tileE[mt];
    int row0 = tileRow[mt];

    __shared__ __align__(16) u16 As[128 * 64];
    __shared__ __align__(16) u16 Bs[128 * 64];

    int tid = threadIdx.x;
    int wave = tid >> 6, lane = tid & 63;
    int laneR = lane & 15, kgrp = lane >> 4;

    const u16* gA[4]; const u16* gB[4];
    #pragma unroll
    for (int i = 0; i < 4; i++) {
        int c = i * 256 + tid;
        int r = c >> 3, kc = c & 7;
        int kcs = kc ^ (r & 7);
        gA[i] = Hact + (size_t)(row0 + r) * FD + kcs * 8;
        gB[i] = W2t + ((size_t)e * HD + (n0 + r)) * FD + kcs * 8;
    }
    char* AsB = (char*)As; char* BsB = (char*)Bs;

    f32x4 acc[4][4] = {};

    int wr = wave >> 1, wc = wave & 1;
    int off0 = ((kgrp ^ (lane & 7)) << 4);
    int off1 = off0 ^ 64;
    const char* Abase = AsB + (wr * 64 + laneR) * 128;
    const char* Bbase = BsB + (wc * 64 + laneR) * 128;

    for (int kt = 0; kt < FD / 64; kt++) {
        #pragma unroll
        for (int i = 0; i < 4; i++)
            GLOAD16(gA[i], AsB + i * 4096 + wave * 1024);
        #pragma unroll
        for (int i = 0; i < 4; i++)
            GLOAD16(gB[i], BsB + i * 4096 + wave * 1024);
        #pragma unroll
        for (int i = 0; i < 4; i++) { gA[i] += 64; gB[i] += 64; }
        __syncthreads();
        #pragma unroll
        for (int kk = 0; kk < 2; kk++) {
            int off = kk ? off1 : off0;
            bf16x8 a[4], b[4];
            #pragma unroll
            for (int m = 0; m < 4; m++) a[m] = *(const bf16x8*)(Abase + m * 2048 + off);
            #pragma unroll
            for (int n = 0; n < 4; n++) b[n] = *(const bf16x8*)(Bbase + n * 2048 + off);
            #pragma unroll
            for (int m = 0; m < 4; m++)
                #pragma unroll
                for (int n = 0; n < 4; n++)
                    acc[m][n] = __builtin_amdgcn_mfma_f32_16x16x32_bf16(b[n], a[m], acc[m][n], 0, 0, 0);
        }
        __syncthreads();
    }

    // epilogue (swapped layout): 1 rid lookup per mf; cvt_pk + 8B stores
    const float* b2e = b2 + e * HD + n0;
    int pc = padcum[e];
    #pragma unroll
    for (int mf = 0; mf < 4; mf++) {
        int rr = row0 + wr * 64 + mf * 16 + laneR;
        int rid = sorted_rid[rr];
        if (rid < 0) continue;               // padding row: no storage
        u16* orow = Out2 + (size_t)(rr - pc) * HD + n0;
        #pragma unroll
        for (int nf = 0; nf < 4; nf++) {
            int c = wc * 64 + nf * 16 + kgrp * 4;
            float4 bb = *(const float4*)(b2e + c);
            float v0 = acc[mf][nf][0] + bb.x;
            float v1 = acc[mf][nf][1] + bb.y;
            float v2 = acc[mf][nf][2] + bb.z;
            float v3 = acc[mf][nf][3] + bb.w;
            uint2 p = make_uint2(pk_bf16(v0, v1), pk_bf16(v2, v3));
            *(uint2*)(orow + c) = p;
        }
    }
}

// ---------------- combine: y[t] = w0*Out2[inv[2t]] + w1*Out2[inv[2t+1]] ----------------

__global__ void combine_kernel(const u16* __restrict__ Out2, const int* __restrict__ inv,
                               const float* __restrict__ ew, float* __restrict__ y) {
    int i = blockIdx.x * blockDim.x + threadIdx.x;   // one thread = 8 cols of one token
    int tok = i >> 7;
    int c0 = (i & 127) << 3;
    int s0 = inv[2 * tok], s1 = inv[2 * tok + 1];
    float w0 = ew[2 * tok], w1 = ew[2 * tok + 1];
    union { uint4 v; u16 s[8]; } a, b;
    a.v = *(const uint4*)(Out2 + (size_t)s0 * HD + c0);
    b.v = *(const uint4*)(Out2 + (size_t)s1 * HD + c0);
    float out[8];
    #pragma unroll
    for (int j = 0; j < 8; j++) {
        union { u32 u; float f; } fa, fb;
        fa.u = (u32)a.s[j] << 16;
        fb.u = (u32)b.s[j] << 16;
        out[j] = w0 * fa.f + w1 * fb.f;
    }
    float4* yp = (float4*)(y + (size_t)tok * HD + c0);
    yp[0] = *(const float4*)&out[0];
    yp[1] = *(const float4*)&out[4];
}

// ---------------- launch ----------------

extern "C" void kernel_launch(void* const* d_in, const int* in_sizes, int n_in,
                              void* d_out, int out_size, void* d_ws, size_t ws_size,
                              hipStream_t stream) {
    const float* x  = (const float*)d_in[0];
    const float* ew = (const float*)d_in[1];
    const int*   te = (const int*)d_in[2];
    const float* w1 = (const float*)d_in[3];
    const float* b1 = (const float*)d_in[4];
    const float* w2 = (const float*)d_in[5];
    const float* b2 = (const float*)d_in[6];
    float* y = (float*)d_out;

    char* ws = (char*)d_ws;
    // Xb[0,32M) W1t[32M,64M) W2t[64M,96M) Hact[96M,228M) ip[228M+]
    // Out2 (compacted, 32768 x 1024 bf16 = 64MB) overlays Xb+W1t.
    u16* Xb   = (u16*)(ws);                      // 33,554,432 B
    u16* W1t  = (u16*)(ws + 33554432);           // 33,554,432 B
    u16* Out2 = (u16*)(ws);                      // 67,108,864 B (overlay)
    u16* W2t  = (u16*)(ws + 67108864);           // 33,554,432 B
    u16* Hact = (u16*)(ws + 100663296);          // 138,412,032 B (RP_MAX x 2048 bf16)
    char* ip  = ws + 239075328;
    int* numTiles = (int*)(ip);
    int* padcum   = (int*)(ip + 64);
    int* tileE    = (int*)(ip + 128);            // 1056 B
    int* tileRow  = (int*)(ip + 2048);           // 1056 B
    int* sorted   = (int*)(ip + 4096);           // 135,168 B
    int* inv      = (int*)(ip + 139264);         // 131,072 B

    // fused prep: routing (bid 0, overlaps) | convert_x | w1^T | w2^T
    mega_prep<<<NB_PREP, 1024, 0, stream>>>(
        x, Xb, w1, W1t, w2, W2t, te, sorted, inv, tileE, tileRow, numTiles, padcum);

    // grouped GEMM 1 (nt-fast decode: pin gathered A-panel in L2)
    gemm1_kernel<<<G1_BLOCKS, 256, 0, stream>>>(
        Xb, W1t, b1, sorted, tileE, tileRow, numTiles, Hact);

    // grouped GEMM 2 (mt-quad decode: share B-panel across 4 m-tiles)
    gemm2_kernel<<<G2_BLOCKS, 256, 0, stream>>>(
        Hact, W2t, b2, sorted, padcum, tileE, tileRow, numTiles, Out2);

    // weighted topk combine
    combine_kernel<<<(TOKENS * 128) / 256, 256, 0, stream>>>(Out2, inv, ew, y);
}